// Round 7
// baseline (101.019 us; speedup 1.0000x reference)
//
#include <hip/hip_runtime.h>
#include <stdint.h>

#define G_NUM 4096
#define BLOCK 256
#define WPB   4                  // waves per block (1 graph per wave)
#define CAP   3069               // max staged segment len (mean 2048, sd ~45 -> 22 sigma)
#define KCAP  3072               // k16 entries per wave (covers [a0, a0+3072))
#define HB    512                // histogram buckets (9 bits of 16-bit truncated key)
#define CLS   384                // boundary-class capacity

typedef unsigned long long ull;

// wave-synchronous LDS fence: waits all LDS ops, blocks compiler reordering
__device__ __forceinline__ void wsync() {
    asm volatile("s_waitcnt lgkmcnt(0)" ::: "memory");
}

__device__ __forceinline__ unsigned int order_bits(float f) {
    unsigned int b = __float_as_uint(f);
    return (b & 0x80000000u) ? ~b : (b | 0x80000000u);
}
__device__ __forceinline__ float inv_order_bits(unsigned int ob) {
    return __uint_as_float((ob & 0x80000000u) ? (ob & 0x7FFFFFFFu) : ~ob);
}

// start[] via per-graph binary search (batch sorted) + mask dtype detect.
// flag: 0 = int32/float mask (word test), 2 = byte (bool) mask
__global__ void prep_kernel(const int* __restrict__ batch, int* __restrict__ start,
                            const unsigned int* __restrict__ mraw, int* __restrict__ flag,
                            int E) {
    if (blockIdx.x == 0 && threadIdx.x < 64) {
        int lane = threadIdx.x;
        bool allI = true, allF = true;
        for (int i = lane; i < 256; i += 64) {
            unsigned int w = mraw[i];
            if (w > 1u) allI = false;
            if (w != 0u && w != 0x3F800000u) allF = false;
        }
        allI = __all(allI);
        allF = __all(allF);
        if (lane == 0) *flag = allI ? 0 : (allF ? 1 : 2);
    }
    int t = blockIdx.x * blockDim.x + threadIdx.x;
    if (t > G_NUM) return;
    if (t == G_NUM) { start[G_NUM] = E; return; }
    int lo = 0, hi = E;                 // lower_bound: first i with batch[i] >= t
    while (lo < hi) {
        int mid = (lo + hi) >> 1;
        if (batch[mid] < t) lo = mid + 1; else hi = mid;
    }
    start[t] = lo;
}

// Wave-level k-th bucket select over NPT*64 buckets (lane owns [lane*NPT, +NPT)).
// Suffix order: higher bucket = higher key. Self-clears hist[0 .. NPT*64).
// Returns (bsel, cgt = count in buckets > bsel, csel = count in bsel), wave-uniform.
template <int NPT>
__device__ __forceinline__ void wave_sel(unsigned int* hist, int lane, int kk,
                                         int& bsel, unsigned int& cgt, unsigned int& csel)
{
    unsigned int h[NPT];
    unsigned int S = 0u;
    const int b0 = lane * NPT;
    #pragma unroll
    for (int j = 0; j < NPT; ++j) { h[j] = hist[b0 + j]; S += h[j]; hist[b0 + j] = 0u; }
    unsigned int v = S;
    #pragma unroll
    for (int off = 1; off < 64; off <<= 1) {
        unsigned int o = __shfl_down(v, off, 64);
        if (lane + off < 64) v += o;
    }
    unsigned int run = v - S;            // keys in lanes strictly above me
    int fj = -1; unsigned int fc = 0u, fs = 0u;
    #pragma unroll
    for (int j = NPT - 1; j >= 0; --j) {
        unsigned int inc = run + h[j];
        if (fj < 0 && (unsigned)kk <= inc && (unsigned)kk > run) { fj = j; fc = run; fs = h[j]; }
        run = inc;
    }
    ull bm = __ballot(fj >= 0);
    int wl = (int)(__ffsll((long long)bm) - 1);
    bsel = __shfl(b0 + fj, wl);
    cgt  = __shfl(fc, wl);
    csel = __shfl(fs, wl);
}

__global__ __launch_bounds__(BLOCK) void topk_kernel(
    const float* __restrict__ scores, const void* __restrict__ maskp,
    const int* __restrict__ start, const int* __restrict__ kp,
    const int* __restrict__ flagp, float* __restrict__ out_mask,
    float* __restrict__ out_scores, int E)
{
    __shared__ unsigned short k16s[WPB][KCAP];
    __shared__ unsigned int   hists[WPB][HB];

    const int tid  = threadIdx.x;
    const int lane = tid & 63;
    const int w    = tid >> 6;
    const int g    = blockIdx.x * WPB + w;

    const int s0 = start[g];
    const int s1 = start[g + 1];
    const int len = s1 - s0;
    if (len <= 0) return;

    const int k     = *kp;
    const int mflag = *flagp;
    unsigned short* k16 = k16s[w];
    unsigned int*  hist = hists[w];

    auto getmask = [&](int i) -> bool {
        if (mflag == 2) return ((const unsigned char*)maskp)[i] != 0;
        return ((const int*)maskp)[i] != 0;     // int32 or float: nonzero word test
    };

    if (k <= 0) {
        for (int i = s0 + lane; i < s1; i += 64) { out_mask[i] = 0.0f; out_scores[i] = 0.0f; }
        return;
    }

    if (len <= CAP) {
        const int a0 = s0 & ~3;           // 16B-aligned base
        const int dl = a0 - s0;           // <=0
        const int nch = (s1 - a0 + 255) >> 8;

        auto load_cm4 = [&](int g0) -> unsigned int {
            unsigned int cm4 = 0u;
            if (mflag == 2) {
                unsigned int mw = *(const unsigned int*)((const unsigned char*)maskp + g0);
                if (mw & 0x000000FFu) cm4 |= 1u;
                if (mw & 0x0000FF00u) cm4 |= 2u;
                if (mw & 0x00FF0000u) cm4 |= 4u;
                if (mw & 0xFF000000u) cm4 |= 8u;
            } else {
                int4 mw = *(const int4*)((const int*)maskp + g0);
                if (mw.x) cm4 |= 1u; if (mw.y) cm4 |= 2u;
                if (mw.z) cm4 |= 4u; if (mw.w) cm4 |= 8u;
            }
            return cm4;
        };
        // loads 4 keys of chunk q; returns cand mask (bits 0..3)
        auto load_chunk = [&](int q, unsigned int kk4[4]) -> unsigned int {
            const int g0 = a0 + 4 * (q * 64 + lane);
            unsigned int cm4 = 0u;
            if (g0 >= s0 && g0 + 4 <= s1) {
                float4 f = *(const float4*)(scores + g0);
                kk4[0] = order_bits(f.x); kk4[1] = order_bits(f.y);
                kk4[2] = order_bits(f.z); kk4[3] = order_bits(f.w);
                cm4 = load_cm4(g0);
            } else {
                #pragma unroll
                for (int j = 0; j < 4; ++j) {
                    int gi = g0 + j; kk4[j] = 0u;
                    if (gi >= s0 && gi < s1) {
                        kk4[j] = order_bits(scores[gi]);
                        if (getmask(gi)) cm4 |= 1u << j;
                    }
                }
            }
            return cm4;
        };

        // ---- zero hist ----
        #pragma unroll
        for (int j = 0; j < HB / 64; ++j) hist[lane + j * 64] = 0u;
        wsync();

        // ---- sweep 1: stage 16-bit keys to LDS, histogram, count ----
        int lc = 0;
        for (int q = 0; q < nch; ++q) {
            unsigned int kk4[4];
            unsigned int cm4 = load_chunk(q, kk4);
            ushort4 hv; unsigned short* hp = (unsigned short*)&hv;
            #pragma unroll
            for (int j = 0; j < 4; ++j) {
                unsigned int h = kk4[j] >> 16; h += (h == 0u);   // clamp: cand stored >=1
                bool c = (cm4 >> j) & 1u;
                hp[j] = c ? (unsigned short)h : (unsigned short)0;
                if (c) atomicAdd(&hist[h >> 7], 1u);
            }
            *(ushort4*)&k16[4 * (q * 64 + lane)] = hv;
            lc += __popc(cm4);
        }
        #pragma unroll
        for (int off = 1; off < 64; off <<= 1) lc += __shfl_xor(lc, off, 64);
        const int m = lc;                 // wave-uniform
        wsync();

        const bool keepall = (m <= k);
        unsigned int P32 = 0u;
        int licut = 0;

        if (!keepall) {
            int bsel; unsigned int cgt, csel;
            wave_sel<HB / 64>(hist, lane, k, bsel, cgt, csel);
            int kk2 = k - (int)cgt;       // rank inside selected bucket

            if (csel <= CLS) {
                // ---- collect bucket members (entries = offset idx from a0) ----
                wsync();                   // wave_sel's clears visible (counter at HB-1 = 0)
                const int tot = nch * 256;
                for (int idx = lane; idx < tot; idx += 64) {
                    unsigned int h = k16[idx];
                    if (h != 0u && (int)(h >> 7) == bsel)
                        hist[atomicAdd(&hist[HB - 1], 1u)] = (unsigned int)idx;
                }
                wsync();
                // ---- gather exact keys into (reused) k16 region ----
                unsigned int* kst = (unsigned int*)k16;
                for (int e = lane; e < (int)csel; e += 64)
                    kst[e] = order_bits(scores[a0 + (int)hist[e]]);
                wsync();
                // ---- exact rank by (key32, idx) ----
                bool found = false; unsigned int fP = 0u; int fL = 0;
                for (int e = lane; e < (int)csel; e += 64) {
                    unsigned int idx = hist[e], key = kst[e];
                    int r = 0;
                    for (int j = 0; j < (int)csel; ++j) {
                        unsigned int kj = kst[j], ij = hist[j];
                        if (kj > key || (kj == key && ij < idx)) r++;
                    }
                    if (r == kk2 - 1) { found = true; fP = key; fL = (int)idx + dl; }
                }
                ull bm = __ballot(found);
                int wl = (int)(__ffsll((long long)bm) - 1);
                P32 = __shfl(fP, wl); licut = __shfl(fL, wl);
            } else {
                // ---- rare: refine exact key bits [22:16],[15:8],[7:0] via global rescans ----
                unsigned int pfx = ((unsigned int)bsel) << 23;  // bucket == key32>>23 (clamp-safe)
                const int lows[3] = {16, 8, 0};
                const int wids[3] = {7, 8, 8};
                for (int r = 0; r < 3; ++r) {
                    const int L = lows[r], W = wids[r];
                    const unsigned int dm = (1u << W) - 1u;
                    wsync();
                    for (int q = 0; q < nch; ++q) {
                        unsigned int kk4[4];
                        unsigned int cm4 = load_chunk(q, kk4);
                        #pragma unroll
                        for (int j = 0; j < 4; ++j)
                            if (((cm4 >> j) & 1u) && ((kk4[j] >> (L + W)) == (pfx >> (L + W))))
                                atomicAdd(&hist[(kk4[j] >> L) & dm], 1u);
                    }
                    wsync();
                    int b2; unsigned int cg2, cs2;
                    if (W == 7) wave_sel<2>(hist, lane, kk2, b2, cg2, cs2);
                    else        wave_sel<4>(hist, lane, kk2, b2, cg2, cs2);
                    pfx |= ((unsigned int)b2) << L;
                    kk2 -= (int)cg2;
                }
                P32 = pfx;
                // li binary search among key32 == P32 (>CLS identical keys)
                int lo = 0, hi = len - 1;
                while (lo < hi) {
                    int mid = (lo + hi) >> 1;
                    int c = 0;
                    for (int q = 0; q < nch; ++q) {
                        unsigned int kk4[4];
                        unsigned int cm4 = load_chunk(q, kk4);
                        const int g0 = a0 + 4 * (q * 64 + lane);
                        #pragma unroll
                        for (int j = 0; j < 4; ++j)
                            if (((cm4 >> j) & 1u) && kk4[j] == P32 && (g0 + j - s0) <= mid) c++;
                    }
                    #pragma unroll
                    for (int off = 1; off < 64; off <<= 1) c += __shfl_xor(c, off, 64);
                    if (c >= kk2) hi = mid; else lo = mid + 1;
                }
                licut = lo;
            }
        }

        // ---- output sweep (re-read, L2/L3-hot), coalesced float4 ----
        for (int q = 0; q < nch; ++q) {
            const int g0 = a0 + 4 * (q * 64 + lane);
            unsigned int kk4[4];
            unsigned int cm4 = load_chunk(q, kk4);
            if (g0 >= s0 && g0 + 4 <= s1) {
                float4 vm, vs;
                float* pm = (float*)&vm; float* ps = (float*)&vs;
                #pragma unroll
                for (int j = 0; j < 4; ++j) {
                    int li = g0 + j - s0;
                    bool kept = ((cm4 >> j) & 1u) &&
                        (keepall || kk4[j] > P32 || (kk4[j] == P32 && li <= licut));
                    pm[j] = kept ? 1.0f : 0.0f;
                    ps[j] = kept ? inv_order_bits(kk4[j]) : 0.0f;
                }
                *(float4*)(out_mask   + g0) = vm;
                *(float4*)(out_scores + g0) = vs;
            } else if (g0 < s1) {
                #pragma unroll
                for (int j = 0; j < 4; ++j) {
                    int gi = g0 + j;
                    if (gi < s0 || gi >= s1) continue;
                    int li = gi - s0;
                    bool kept = ((cm4 >> j) & 1u) &&
                        (keepall || kk4[j] > P32 || (kk4[j] == P32 && li <= licut));
                    out_mask[gi]   = kept ? 1.0f : 0.0f;
                    out_scores[gi] = kept ? inv_order_bits(kk4[j]) : 0.0f;
                }
            }
        }
    } else {
        // ---- fallback: wave-level global-rescan 64-bit radix (len > CAP; ~never) ----
        #pragma unroll
        for (int j = 0; j < 4; ++j) hist[lane + j * 64] = 0u;
        int lc = 0;
        for (int i = s0 + lane; i < s1; i += 64)
            if (getmask(i)) lc++;
        #pragma unroll
        for (int off = 1; off < 64; off <<= 1) lc += __shfl_xor(lc, off, 64);
        const int m = lc;
        const bool keepall = (m <= k);
        ull pivot = 0ull;
        if (!keepall) {
            ull pfx = 0ull;
            int kk = k;
            for (int shift = 56; shift >= 0; shift -= 8) {
                wsync();
                for (int i = s0 + lane; i < s1; i += 64) {
                    if (!getmask(i)) continue;
                    ull key = ((ull)order_bits(scores[i]) << 32) |
                              (ull)(0xFFFFFFFFu - (unsigned)(i - s0));
                    if (shift == 56 || (key >> (shift + 8)) == (pfx >> (shift + 8)))
                        atomicAdd(&hist[(unsigned)((key >> shift) & 0xFFull)], 1u);
                }
                wsync();
                int b; unsigned int cg, cs;
                wave_sel<4>(hist, lane, kk, b, cg, cs);
                pfx |= ((ull)(unsigned)b) << shift;
                kk -= (int)cg;
            }
            pivot = pfx;
        }
        for (int i = s0 + lane; i < s1; i += 64) {
            bool c = getmask(i);
            float sc = 0.0f;
            bool kept = false;
            if (c) {
                sc = scores[i];
                ull key = ((ull)order_bits(sc) << 32) |
                          (ull)(0xFFFFFFFFu - (unsigned)(i - s0));
                kept = keepall || (key >= pivot);
            }
            out_mask[i]   = kept ? 1.0f : 0.0f;
            out_scores[i] = kept ? sc : 0.0f;
        }
    }
}

extern "C" void kernel_launch(void* const* d_in, const int* in_sizes, int n_in,
                              void* d_out, int out_size, void* d_ws, size_t ws_size,
                              hipStream_t stream) {
    const float* scores = (const float*)d_in[0];
    const int*   batch  = (const int*)d_in[1];
    const void*  mask   = d_in[2];
    const int*   kp     = (const int*)d_in[4];
    const int    E      = in_sizes[0];

    float* out_mask   = (float*)d_out;
    float* out_scores = out_mask + E;

    int* flag  = (int*)d_ws;
    int* start = (int*)((char*)d_ws + 256);

    prep_kernel<<<(G_NUM + 1 + BLOCK - 1) / BLOCK, BLOCK, 0, stream>>>(
        batch, start, (const unsigned int*)mask, flag, E);
    topk_kernel<<<G_NUM / WPB, BLOCK, 0, stream>>>(scores, mask, start, kp, flag,
                                                   out_mask, out_scores, E);
}

// Round 8
// 53.928 us; speedup vs baseline: 1.8732x; 1.8732x over previous
//
#include <hip/hip_runtime.h>
#include <stdint.h>

#define G_NUM 4096
#define BLOCK 256
#define WPB   4                    // waves per block, 1 graph per wave
#define WCH   12                   // float4 chunks per lane (48 elems/lane)
#define CAPW  (64 * 4 * WCH - 3)   // 3069; mean seg len 2048, sd ~45 -> 22 sigma
#define HBW   1024                 // per-wave histogram buckets (10-bit radix)
#define CLSW  128                  // per-wave boundary-class capacity

typedef unsigned long long ull;

// wave-synchronous LDS fence (no s_barrier anywhere in this kernel)
__device__ __forceinline__ void wsync() {
    asm volatile("s_waitcnt lgkmcnt(0)" ::: "memory");
}

__device__ __forceinline__ unsigned int order_bits(float f) {
    unsigned int b = __float_as_uint(f);
    return (b & 0x80000000u) ? ~b : (b | 0x80000000u);
}
__device__ __forceinline__ float inv_order_bits(unsigned int ob) {
    return __uint_as_float((ob & 0x80000000u) ? (ob & 0x7FFFFFFFu) : ~ob);
}
// bank-transposed physical slot for logical bucket b in [0,1024):
// reads of 16 consecutive logical buckets by lane l land at stride-64 words
// -> bank = lane%32 (2-way, free). Bijective on [0,1024).
__device__ __forceinline__ int physb(int b) { return ((b & 15) << 6) | (b >> 4); }

// start[] via per-graph binary search (batch sorted) + mask dtype detect.
// flag: 2 = byte (bool) mask, else 32-bit word mask (int/float nonzero)
__global__ void prep_kernel(const int* __restrict__ batch, int* __restrict__ start,
                            const unsigned int* __restrict__ mraw, int* __restrict__ flag,
                            int E) {
    if (blockIdx.x == 0 && threadIdx.x < 64) {
        int lane = threadIdx.x;
        bool allI = true, allF = true;
        for (int i = lane; i < 256; i += 64) {
            unsigned int w = mraw[i];
            if (w > 1u) allI = false;
            if (w != 0u && w != 0x3F800000u) allF = false;
        }
        allI = __all(allI);
        allF = __all(allF);
        if (lane == 0) *flag = (allI || allF) ? 0 : 2;
    }
    int t = blockIdx.x * blockDim.x + threadIdx.x;
    if (t > G_NUM) return;
    if (t == G_NUM) { start[G_NUM] = E; return; }
    int lo = 0, hi = E;
    while (lo < hi) {
        int mid = (lo + hi) >> 1;
        if (batch[mid] < t) lo = mid + 1; else hi = mid;
    }
    start[t] = lo;
}

// Wave-local k-th bucket select over NPT*64 buckets (lane owns [lane*NPT,+NPT)
// logical, phys-mapped). Self-clears. Returns bucket, count-above, bucket count,
// and grand total; all wave-uniform. Zero barriers.
template <int NPT>
__device__ __forceinline__ void wave_sel(unsigned int* hist, int lane, int kk,
                                         int& bsel, unsigned int& cgt,
                                         unsigned int& csel, unsigned int& mtot)
{
    unsigned int h[NPT];
    unsigned int S = 0u;
    const int b0 = lane * NPT;
    #pragma unroll
    for (int j = 0; j < NPT; ++j) {
        int pb = physb(b0 + j);
        h[j] = hist[pb]; S += h[j]; hist[pb] = 0u;
    }
    unsigned int v = S;
    #pragma unroll
    for (int off = 1; off < 64; off <<= 1) {
        unsigned int o = __shfl_down(v, off, 64);
        if (lane + off < 64) v += o;
    }
    mtot = __shfl(v, 0, 64);
    unsigned int run = v - S;            // strictly above my bucket range
    int fj = -1; unsigned int fc = 0u, fs = 0u;
    #pragma unroll
    for (int j = NPT - 1; j >= 0; --j) {
        unsigned int inc = run + h[j];
        if (fj < 0 && (unsigned)kk <= inc && (unsigned)kk > run) { fj = j; fc = run; fs = h[j]; }
        run = inc;
    }
    ull bm = __ballot(fj >= 0);
    int wl = (int)(__ffsll((long long)bm) - 1);
    bsel = __shfl(b0 + fj, wl, 64);
    cgt  = __shfl(fc, wl, 64);
    csel = __shfl(fs, wl, 64);
}

__global__ __launch_bounds__(BLOCK, 4) void topk_kernel(
    const float* __restrict__ scores, const void* __restrict__ maskp,
    const int* __restrict__ start, const int* __restrict__ kp,
    const int* __restrict__ flagp, float* __restrict__ out_mask,
    float* __restrict__ out_scores, int E)
{
    __shared__ unsigned int hist_s[WPB][HBW];
    __shared__ ull          cls_s[WPB][CLSW];
    __shared__ unsigned int ccnt_s[WPB];

    const int tid  = threadIdx.x;
    const int lane = tid & 63;
    const int w    = tid >> 6;
    const int g    = blockIdx.x * WPB + w;

    const int s0 = start[g];
    const int s1 = start[g + 1];
    const int len = s1 - s0;
    if (len <= 0) return;

    const int k     = *kp;
    const int mflag = *flagp;
    unsigned int* hist = hist_s[w];
    ull*          cls  = cls_s[w];

    auto getmask = [&](int i) -> bool {
        if (mflag == 2) return ((const unsigned char*)maskp)[i] != 0;
        return ((const int*)maskp)[i] != 0;
    };

    if (k <= 0) {
        for (int i = s0 + lane; i < s1; i += 64) { out_mask[i] = 0.0f; out_scores[i] = 0.0f; }
        return;
    }

    if (len <= CAPW) {
        const int a0 = s0 & ~3;
        const int dl = a0 - s0;
        unsigned int key[4 * WCH];
        ull candm = 0ull;

        // ---- clear per-wave LDS (in-order DS pipe: safe before atomics) ----
        #pragma unroll
        for (int j = 0; j < HBW / 64; ++j) hist[physb(lane + 64 * j)] = 0u;
        if (lane == 0) ccnt_s[w] = 0u;

        // ---- register-resident load: 12 coalesced float4 + mask chunks ----
        #pragma unroll
        for (int q = 0; q < WCH; ++q) {
            const int g0 = a0 + 4 * (q * 64 + lane);
            unsigned int cm4 = 0u;
            if (g0 >= s0 && g0 + 4 <= s1) {
                float4 f = *(const float4*)(scores + g0);
                key[4*q+0] = order_bits(f.x); key[4*q+1] = order_bits(f.y);
                key[4*q+2] = order_bits(f.z); key[4*q+3] = order_bits(f.w);
                if (mflag == 2) {
                    unsigned int mw = *(const unsigned int*)((const unsigned char*)maskp + g0);
                    if (mw & 0x000000FFu) cm4 |= 1u;
                    if (mw & 0x0000FF00u) cm4 |= 2u;
                    if (mw & 0x00FF0000u) cm4 |= 4u;
                    if (mw & 0xFF000000u) cm4 |= 8u;
                } else {
                    int4 mw = *(const int4*)((const int*)maskp + g0);
                    if (mw.x) cm4 |= 1u; if (mw.y) cm4 |= 2u;
                    if (mw.z) cm4 |= 4u; if (mw.w) cm4 |= 8u;
                }
            } else if (g0 < s1 && g0 + 4 > s0) {      // partial edge chunk
                #pragma unroll
                for (int j = 0; j < 4; ++j) {
                    int gi = g0 + j; key[4*q+j] = 0u;
                    if (gi >= s0 && gi < s1) {
                        key[4*q+j] = order_bits(scores[gi]);
                        if (getmask(gi)) cm4 |= 1u << j;
                    }
                }
            } else {
                #pragma unroll
                for (int j = 0; j < 4; ++j) key[4*q+j] = 0u;
            }
            candm |= (ull)cm4 << (4 * q);
        }
        wsync();                                      // clears complete

        // ---- per-wave histogram (bucket = key>>22, phys-mapped) ----
        #pragma unroll
        for (int v = 0; v < 4 * WCH; ++v)
            if ((candm >> v) & 1ull) atomicAdd(&hist[physb((int)(key[v] >> 22))], 1u);
        wsync();

        int bsel; unsigned int cgt, csel, m;
        wave_sel<HBW / 64>(hist, lane, k, bsel, cgt, csel, m);

        const bool keepall = (m <= (unsigned)k);
        unsigned int P = 0u;
        int licut = 0x7FFFFFFF;

        if (!keepall) {
            int kk2 = k - (int)cgt;                   // 1..csel

            if (csel <= CLSW) {
                // ---- collect boundary class into per-wave LDS ----
                #pragma unroll
                for (int v = 0; v < 4 * WCH; ++v) {
                    if (((candm >> v) & 1ull) && (int)(key[v] >> 22) == bsel) {
                        int q = v >> 2;
                        int li = dl + 4 * (q * 64 + lane) + (v & 3);
                        cls[atomicAdd(&ccnt_s[w], 1u)] = ((ull)key[v] << 32) | (unsigned)li;
                    }
                }
                wsync();
                bool found = false; unsigned int fP = 0u; int fL = 0;
                if (csel <= 64) {
                    // shuffle all-pairs rank, one entry per lane
                    ull me = (lane < (int)csel) ? cls[lane] : 0ull;
                    unsigned int mk = (unsigned int)(me >> 32), ml = (unsigned int)me;
                    int r = 0;
                    for (int j = 0; j < (int)csel; ++j) {
                        ull o = __shfl(me, j, 64);
                        unsigned int ok = (unsigned int)(o >> 32), ol = (unsigned int)o;
                        r += (ok > mk || (ok == mk && ol < ml)) ? 1 : 0;
                    }
                    if (lane < (int)csel && r == kk2 - 1) { found = true; fP = mk; fL = (int)ml; }
                } else {
                    for (int e = lane; e < (int)csel; e += 64) {
                        ull me = cls[e];
                        unsigned int mk = (unsigned int)(me >> 32), ml = (unsigned int)me;
                        int r = 0;
                        for (int j = 0; j < (int)csel; ++j) {
                            ull o = cls[j];
                            unsigned int ok = (unsigned int)(o >> 32), ol = (unsigned int)o;
                            r += (ok > mk || (ok == mk && ol < ml)) ? 1 : 0;
                        }
                        if (r == kk2 - 1) { found = true; fP = mk; fL = (int)ml; }
                    }
                }
                ull bm = __ballot(found);
                int wl = (int)(__ffsll((long long)bm) - 1);
                P = __shfl(fP, wl, 64); licut = __shfl(fL, wl, 64);
            } else {
                // ---- rare: refine remaining 22 key bits from registers ----
                unsigned int pfx = ((unsigned int)bsel) << 22;
                const int lows[3] = {14, 6, 0};
                const int wids[3] = {8, 8, 6};
                #pragma unroll
                for (int r = 0; r < 3; ++r) {
                    const int L = lows[r], W = wids[r];
                    const unsigned int dm = (1u << W) - 1u;
                    #pragma unroll
                    for (int v = 0; v < 4 * WCH; ++v)
                        if (((candm >> v) & 1ull) &&
                            ((key[v] >> (L + W)) == (pfx >> (L + W))))
                            atomicAdd(&hist[physb((int)((key[v] >> L) & dm))], 1u);
                    wsync();
                    int b2; unsigned int cg2, cs2, mt2;
                    if (W == 8) wave_sel<4>(hist, lane, kk2, b2, cg2, cs2, mt2);
                    else        wave_sel<1>(hist, lane, kk2, b2, cg2, cs2, mt2);
                    pfx |= ((unsigned int)b2) << L;
                    kk2 -= (int)cg2;
                }
                P = pfx;
                // licut: binary search on li among key==P (register rescan)
                int lo = 0, hi = len - 1;
                while (lo < hi) {
                    int mid = (lo + hi) >> 1;
                    int c = 0;
                    #pragma unroll
                    for (int v = 0; v < 4 * WCH; ++v) {
                        int q = v >> 2;
                        int li = dl + 4 * (q * 64 + lane) + (v & 3);
                        if (((candm >> v) & 1ull) && key[v] == P && li <= mid) c++;
                    }
                    #pragma unroll
                    for (int off = 1; off < 64; off <<= 1) c += __shfl_xor(c, off, 64);
                    if (c >= kk2) hi = mid; else lo = mid + 1;
                }
                licut = lo;
            }
        }

        // ---- terminal coalesced store phase, straight from registers ----
        #pragma unroll
        for (int q = 0; q < WCH; ++q) {
            const int g0 = a0 + 4 * (q * 64 + lane);
            if (g0 >= s0 && g0 + 4 <= s1) {
                float4 vm, vs;
                float* pm = (float*)&vm; float* ps = (float*)&vs;
                #pragma unroll
                for (int j = 0; j < 4; ++j) {
                    int v = 4*q + j;
                    int li = dl + 4 * (q * 64 + lane) + j;
                    bool kept = ((candm >> v) & 1ull) &&
                        (key[v] > P || (key[v] == P && li <= licut));
                    pm[j] = kept ? 1.0f : 0.0f;
                    ps[j] = kept ? inv_order_bits(key[v]) : 0.0f;
                }
                *(float4*)(out_mask   + g0) = vm;
                *(float4*)(out_scores + g0) = vs;
            } else if (g0 < s1 && g0 + 4 > s0) {
                #pragma unroll
                for (int j = 0; j < 4; ++j) {
                    int gi = g0 + j;
                    if (gi < s0 || gi >= s1) continue;
                    int v = 4*q + j;
                    int li = gi - s0;
                    bool kept = ((candm >> v) & 1ull) &&
                        (key[v] > P || (key[v] == P && li <= licut));
                    out_mask[gi]   = kept ? 1.0f : 0.0f;
                    out_scores[gi] = kept ? inv_order_bits(key[v]) : 0.0f;
                }
            }
        }
    } else {
        // ---- fallback: wave-local global-rescan 64-bit radix (len > CAPW) ----
        #pragma unroll
        for (int j = 0; j < 4; ++j) hist[physb(lane * 4 + j)] = 0u;
        int lc = 0;
        for (int i = s0 + lane; i < s1; i += 64)
            if (getmask(i)) lc++;
        #pragma unroll
        for (int off = 1; off < 64; off <<= 1) lc += __shfl_xor(lc, off, 64);
        const int m = lc;
        const bool keepall = (m <= k);
        ull pivot = 0ull;
        if (!keepall) {
            ull pfx = 0ull;
            int kk = k;
            for (int shift = 56; shift >= 0; shift -= 8) {
                wsync();
                for (int i = s0 + lane; i < s1; i += 64) {
                    if (!getmask(i)) continue;
                    ull kv = ((ull)order_bits(scores[i]) << 32) |
                             (ull)(0xFFFFFFFFu - (unsigned)(i - s0));
                    if (shift == 56 || (kv >> (shift + 8)) == (pfx >> (shift + 8)))
                        atomicAdd(&hist[physb((int)((kv >> shift) & 0xFFull))], 1u);
                }
                wsync();
                int b; unsigned int cg, cs, mt;
                wave_sel<4>(hist, lane, kk, b, cg, cs, mt);
                pfx |= ((ull)(unsigned)b) << shift;
                kk -= (int)cg;
            }
            pivot = pfx;
        }
        for (int i = s0 + lane; i < s1; i += 64) {
            bool c = getmask(i);
            float sc = 0.0f;
            bool kept = false;
            if (c) {
                sc = scores[i];
                ull kv = ((ull)order_bits(sc) << 32) |
                         (ull)(0xFFFFFFFFu - (unsigned)(i - s0));
                kept = keepall || (kv >= pivot);
            }
            out_mask[i]   = kept ? 1.0f : 0.0f;
            out_scores[i] = kept ? sc : 0.0f;
        }
    }
}

extern "C" void kernel_launch(void* const* d_in, const int* in_sizes, int n_in,
                              void* d_out, int out_size, void* d_ws, size_t ws_size,
                              hipStream_t stream) {
    const float* scores = (const float*)d_in[0];
    const int*   batch  = (const int*)d_in[1];
    const void*  mask   = d_in[2];
    const int*   kp     = (const int*)d_in[4];
    const int    E      = in_sizes[0];

    float* out_mask   = (float*)d_out;
    float* out_scores = out_mask + E;

    int* flag  = (int*)d_ws;
    int* start = (int*)((char*)d_ws + 1024);

    prep_kernel<<<(G_NUM + 1 + BLOCK - 1) / BLOCK, BLOCK, 0, stream>>>(
        batch, start, (const unsigned int*)mask, flag, E);
    topk_kernel<<<G_NUM / WPB, BLOCK, 0, stream>>>(scores, mask, start, kp, flag,
                                                   out_mask, out_scores, E);
}